// Round 1
// baseline (343.222 us; speedup 1.0000x reference)
//
#include <hip/hip_runtime.h>
#include <hip/hip_bf16.h>

// DilatedAttention (b=4, n=8192, d=1024, w=2048, r=4):
// 16 independent 512x512 self-attentions at d=1024 over gathered tokens
// off + 4*j per segment. alphas==1 (idx unique), so output = scatter(att).

typedef __bf16 bf16_t;
typedef __bf16 bf16x8 __attribute__((ext_vector_type(8)));
typedef float floatx4 __attribute__((ext_vector_type(4)));

#define D_MODEL 1024
#define SEG_W   2048
#define RATE    4
#define M_SUB   512          // tokens per segment after dilation (w/r)
#define NTOK    8192
#define NSEGT   16           // batch(4) * segments(4)
#define XG_ELEMS ((long)NSEGT * M_SUB * D_MODEL)

// ---------------------------------------------------------------------------
// K1: gather x[b, s*2048 + off + 4i, :] -> xg bf16 [seg][i][d]  (row-major)
//                                       -> xgT bf16 [seg][d][i] (transposed)
// 64x64 tiles, LDS transpose. grid = 16 segs * 8 i-tiles * 16 d-tiles = 2048.
// ---------------------------------------------------------------------------
__global__ __launch_bounds__(256) void gather_kernel(
    const float* __restrict__ x, const int* __restrict__ hidp,
    bf16_t* __restrict__ xg, bf16_t* __restrict__ xgT)
{
    const int off = ((hidp[0] % RATE) + RATE) % RATE;
    const int bid = blockIdx.x;
    const int seg = bid >> 7;          // 0..15
    const int rem = bid & 127;
    const int it  = rem >> 4;          // i-tile 0..7
    const int dt  = rem & 15;          // d-tile 0..15
    const int b   = seg >> 2, s = seg & 3;

    __shared__ ushort tile[64][65];    // [i][d], pad to 65 (2-way LDS = free)

    const int t  = threadIdx.x;
    const int r  = t >> 2;             // 0..63
    const int cq = (t & 3) << 4;       // 0,16,32,48

    union U8 { bf16x8 v; ushort u[8]; };

    // phase A: coalesced fp32 read, convert, write xg + LDS tile
    {
        const int  i   = it * 64 + r;
        const long tok = (long)s * SEG_W + off + 4L * i;
        const float* src = x + ((long)b * NTOK + tok) * D_MODEL + dt * 64 + cq;
        float4 f0 = ((const float4*)src)[0];
        float4 f1 = ((const float4*)src)[1];
        float4 f2 = ((const float4*)src)[2];
        float4 f3 = ((const float4*)src)[3];
        U8 lo, hi;
        lo.v[0]=(bf16_t)f0.x; lo.v[1]=(bf16_t)f0.y; lo.v[2]=(bf16_t)f0.z; lo.v[3]=(bf16_t)f0.w;
        lo.v[4]=(bf16_t)f1.x; lo.v[5]=(bf16_t)f1.y; lo.v[6]=(bf16_t)f1.z; lo.v[7]=(bf16_t)f1.w;
        hi.v[0]=(bf16_t)f2.x; hi.v[1]=(bf16_t)f2.y; hi.v[2]=(bf16_t)f2.z; hi.v[3]=(bf16_t)f2.w;
        hi.v[4]=(bf16_t)f3.x; hi.v[5]=(bf16_t)f3.y; hi.v[6]=(bf16_t)f3.z; hi.v[7]=(bf16_t)f3.w;
        bf16_t* dstg = xg + ((long)seg * M_SUB + i) * D_MODEL + dt * 64 + cq;
        *(bf16x8*)(dstg)     = lo.v;
        *(bf16x8*)(dstg + 8) = hi.v;
        #pragma unroll
        for (int j = 0; j < 8; ++j) { tile[r][cq + j] = lo.u[j]; tile[r][cq + 8 + j] = hi.u[j]; }
    }
    __syncthreads();
    // phase B: transposed write xgT (coalesced along i)
    {
        const int dc = r;              // d within tile
        const int iq = cq;             // i within tile
        U8 o0, o1;
        #pragma unroll
        for (int j = 0; j < 8; ++j) { o0.u[j] = tile[iq + j][dc]; o1.u[j] = tile[iq + 8 + j][dc]; }
        bf16_t* dstT = xgT + ((long)seg * D_MODEL + dt * 64 + dc) * M_SUB + it * 64 + iq;
        *(bf16x8*)(dstT)     = o0.v;
        *(bf16x8*)(dstT + 8) = o1.v;
    }
}

// ---------------------------------------------------------------------------
// K2: attention. One block = (seg, 16-row q-tile); 512 blocks, 4 waves.
// Wave w owns keys [w*128, w*128+128) for QK, cols [w*256, w*256+256) for PV.
// MFMA 16x16x32 bf16. Verified layouts (m89/m91/m120):
//   A: m=lane&15, k=quad*8+j   B: n=lane&15, k=quad*8+j
//   D: col=lane&15, row=quad*4+reg
// ---------------------------------------------------------------------------
__global__ __launch_bounds__(256) void attn_kernel(
    const bf16_t* __restrict__ xg, const bf16_t* __restrict__ xgT,
    const int* __restrict__ hidp, float* __restrict__ out)
{
    const int off = ((hidp[0] % RATE) + RATE) % RATE;
    const int bid = blockIdx.x;        // 0..511
    const int seg = bid >> 5;          // 0..15
    const int qt  = bid & 31;          // 0..31
    const int b   = seg >> 2, s = seg & 3;
    const int q0  = qt * 16;

    const int tid  = threadIdx.x;
    const int w    = tid >> 6;
    const int lane = tid & 63;
    const int l16  = lane & 15;
    const int quad = lane >> 4;

    __shared__ float red_max[4][16];
    __shared__ float red_sum[4][16];
    __shared__ alignas(16) ushort P[16][512];   // probs, bf16 bits, [q][key]

    const bf16_t* xseg = xg + (long)seg * M_SUB * D_MODEL;

    // ---- QK^T: scores for 16 q-rows x this wave's 128 keys -> 8 acc tiles
    floatx4 acc[8];
    #pragma unroll
    for (int kt = 0; kt < 8; ++kt) acc[kt] = (floatx4){0.f, 0.f, 0.f, 0.f};

    const bf16_t* qrow = xseg + (long)(q0 + l16) * D_MODEL + quad * 8;
    const bf16_t* krow = xseg + (long)(w * 128 + l16) * D_MODEL + quad * 8;

    for (int kc = 0; kc < 32; ++kc) {          // d-chunks of 32
        bf16x8 A = *(const bf16x8*)(qrow + kc * 32);
        #pragma unroll
        for (int kt = 0; kt < 8; ++kt) {
            bf16x8 B = *(const bf16x8*)(krow + (long)kt * 16 * D_MODEL + kc * 32);
            acc[kt] = __builtin_amdgcn_mfma_f32_16x16x32_bf16(A, B, acc[kt], 0, 0, 0);
        }
    }

    // ---- softmax over 512 keys (4 wave-partials), scale 1/sqrt(1024)
    const float scale = 0.03125f;
    float mx[4];
    #pragma unroll
    for (int j = 0; j < 4; ++j) {
        mx[j] = acc[0][j];
        #pragma unroll
        for (int kt = 1; kt < 8; ++kt) mx[j] = fmaxf(mx[j], acc[kt][j]);
        #pragma unroll
        for (int d = 1; d < 16; d <<= 1) mx[j] = fmaxf(mx[j], __shfl_xor(mx[j], d, 64));
    }
    if (l16 == 0) {
        #pragma unroll
        for (int j = 0; j < 4; ++j) red_max[w][quad * 4 + j] = mx[j];
    }
    __syncthreads();
    float M[4], sm[4];
    #pragma unroll
    for (int j = 0; j < 4; ++j) {
        const int rr = quad * 4 + j;
        M[j] = fmaxf(fmaxf(red_max[0][rr], red_max[1][rr]),
                     fmaxf(red_max[2][rr], red_max[3][rr]));
        sm[j] = 0.f;
    }
    #pragma unroll
    for (int kt = 0; kt < 8; ++kt) {
        #pragma unroll
        for (int j = 0; j < 4; ++j) {
            float p = __expf((acc[kt][j] - M[j]) * scale);
            acc[kt][j] = p;
            sm[j] += p;
        }
    }
    #pragma unroll
    for (int j = 0; j < 4; ++j) {
        #pragma unroll
        for (int d = 1; d < 16; d <<= 1) sm[j] += __shfl_xor(sm[j], d, 64);
    }
    if (l16 == 0) {
        #pragma unroll
        for (int j = 0; j < 4; ++j) red_sum[w][quad * 4 + j] = sm[j];
    }
    __syncthreads();
    float inv[4];
    #pragma unroll
    for (int j = 0; j < 4; ++j) {
        const int rr = quad * 4 + j;
        inv[j] = 1.0f / (red_sum[0][rr] + red_sum[1][rr] + red_sum[2][rr] + red_sum[3][rr]);
    }
    #pragma unroll
    for (int kt = 0; kt < 8; ++kt) {
        #pragma unroll
        for (int j = 0; j < 4; ++j) {
            bf16_t h = (bf16_t)(acc[kt][j] * inv[j]);
            P[quad * 4 + j][w * 128 + kt * 16 + l16] = __builtin_bit_cast(ushort, h);
        }
    }
    __syncthreads();

    // ---- PV: att[16 x 1024] = P[16 x 512] * V[512 x 1024]; wave w: cols w*256..
    bf16x8 Af[16];
    #pragma unroll
    for (int kc = 0; kc < 16; ++kc)
        Af[kc] = *(const bf16x8*)&P[l16][kc * 32 + quad * 8];

    const bf16_t* vbase = xgT + (long)seg * D_MODEL * M_SUB + quad * 8;
    const long tokbase = (long)s * SEG_W + off + 4L * (q0 + quad * 4);
    float* obase = out + (long)b * NTOK * D_MODEL;

    for (int nt = 0; nt < 16; ++nt) {
        const int n = w * 256 + nt * 16 + l16;
        floatx4 a2 = (floatx4){0.f, 0.f, 0.f, 0.f};
        #pragma unroll
        for (int kc = 0; kc < 16; ++kc) {
            bf16x8 B = *(const bf16x8*)(vbase + (long)n * M_SUB + kc * 32);
            a2 = __builtin_amdgcn_mfma_f32_16x16x32_bf16(Af[kc], B, a2, 0, 0, 0);
        }
        #pragma unroll
        for (int j = 0; j < 4; ++j) {
            const long tok = tokbase + 4L * j;
            obase[tok * D_MODEL + n] = a2[j];
        }
    }
}

extern "C" void kernel_launch(void* const* d_in, const int* in_sizes, int n_in,
                              void* d_out, int out_size, void* d_ws, size_t ws_size,
                              hipStream_t stream) {
    const float* x   = (const float*)d_in[0];
    const int*   hid = (const int*)d_in[1];
    float*       out = (float*)d_out;
    bf16_t* xg  = (bf16_t*)d_ws;
    bf16_t* xgT = xg + XG_ELEMS;   // needs 2*16.78 MB = 33.6 MB of ws

    // non-idx rows must be zero (harness poisons d_out with 0xAA)
    hipMemsetAsync(d_out, 0, (size_t)out_size * sizeof(float), stream);
    gather_kernel<<<dim3(2048), dim3(256), 0, stream>>>(x, hid, xg, xgT);
    attn_kernel<<<dim3(512), dim3(256), 0, stream>>>(xg, xgT, hid, out);
}

// Round 2
// 254.490 us; speedup vs baseline: 1.3487x; 1.3487x over previous
//
#include <hip/hip_runtime.h>
#include <hip/hip_bf16.h>

// DilatedAttention (b=4, n=8192, d=1024, w=2048, r=4):
// 16 independent 512x512 self-attentions at d=1024 over gathered tokens
// off + 4*j per segment. alphas==1 (idx unique), so output = scatter(att).
//
// Pipeline: zero(non-idx rows) | gather(x->xg,xgT bf16) ; QK GEMM -> S(bf16,
// scaled) ; rowwise softmax in-place ; PV GEMM -> scatter fp32 store.

typedef __bf16 bf16_t;
typedef __bf16 bf16x8 __attribute__((ext_vector_type(8)));
typedef float floatx4 __attribute__((ext_vector_type(4)));

#define D_MODEL 1024
#define SEG_W   2048
#define RATE    4
#define M_SUB   512          // tokens per segment after dilation (w/r)
#define NTOK    8192
#define NSEGT   16           // batch(4) * segments(4)
#define XG_ELEMS ((long)NSEGT * M_SUB * D_MODEL)
#define S_ELEMS  ((long)NSEGT * M_SUB * M_SUB)

__device__ __forceinline__ void gload16(const bf16_t* g, bf16_t* l) {
    __builtin_amdgcn_global_load_lds(
        (const __attribute__((address_space(1))) void*)g,
        (__attribute__((address_space(3))) void*)l, 16, 0, 0);
}

// ---------------------------------------------------------------------------
// K0: zero all non-idx token rows (PV writes the idx rows). 100 MB.
// ---------------------------------------------------------------------------
__global__ __launch_bounds__(256) void zero_kernel(
    const int* __restrict__ hidp, float* __restrict__ out)
{
    const int off = ((hidp[0] % RATE) + RATE) % RATE;
    const int bid = blockIdx.x;            // 0..24575
    const int b = bid / 6144, j = bid % 6144;
    const int q = j / 3, r2 = j % 3;
    const int t = 4 * q + r2 + (r2 >= off ? 1 : 0);
    float4 z = {0.f, 0.f, 0.f, 0.f};
    ((float4*)(out + ((long)b * NTOK + t) * D_MODEL))[threadIdx.x] = z;
}

// ---------------------------------------------------------------------------
// K1: gather x[b, s*2048 + off + 4i, :] -> xg bf16 [seg][i][d]
//                                       -> xgT bf16 [seg][d][i]
// ---------------------------------------------------------------------------
__global__ __launch_bounds__(256) void gather_kernel(
    const float* __restrict__ x, const int* __restrict__ hidp,
    bf16_t* __restrict__ xg, bf16_t* __restrict__ xgT)
{
    const int off = ((hidp[0] % RATE) + RATE) % RATE;
    const int bid = blockIdx.x;
    const int seg = bid >> 7;          // 0..15
    const int rem = bid & 127;
    const int it  = rem >> 4;          // i-tile 0..7
    const int dt  = rem & 15;          // d-tile 0..15
    const int b   = seg >> 2, s = seg & 3;

    __shared__ ushort tile[64][65];

    const int t  = threadIdx.x;
    const int r  = t >> 2;             // 0..63
    const int cq = (t & 3) << 4;       // 0,16,32,48

    union U8 { bf16x8 v; ushort u[8]; };

    {
        const int  i   = it * 64 + r;
        const long tok = (long)s * SEG_W + off + 4L * i;
        const float* src = x + ((long)b * NTOK + tok) * D_MODEL + dt * 64 + cq;
        float4 f0 = ((const float4*)src)[0];
        float4 f1 = ((const float4*)src)[1];
        float4 f2 = ((const float4*)src)[2];
        float4 f3 = ((const float4*)src)[3];
        U8 lo, hi;
        lo.v[0]=(bf16_t)f0.x; lo.v[1]=(bf16_t)f0.y; lo.v[2]=(bf16_t)f0.z; lo.v[3]=(bf16_t)f0.w;
        lo.v[4]=(bf16_t)f1.x; lo.v[5]=(bf16_t)f1.y; lo.v[6]=(bf16_t)f1.z; lo.v[7]=(bf16_t)f1.w;
        hi.v[0]=(bf16_t)f2.x; hi.v[1]=(bf16_t)f2.y; hi.v[2]=(bf16_t)f2.z; hi.v[3]=(bf16_t)f2.w;
        hi.v[4]=(bf16_t)f3.x; hi.v[5]=(bf16_t)f3.y; hi.v[6]=(bf16_t)f3.z; hi.v[7]=(bf16_t)f3.w;
        bf16_t* dstg = xg + ((long)seg * M_SUB + i) * D_MODEL + dt * 64 + cq;
        *(bf16x8*)(dstg)     = lo.v;
        *(bf16x8*)(dstg + 8) = hi.v;
        #pragma unroll
        for (int j = 0; j < 8; ++j) { tile[r][cq + j] = lo.u[j]; tile[r][cq + 8 + j] = hi.u[j]; }
    }
    __syncthreads();
    {
        const int dc = r;
        const int iq = cq;
        U8 o0, o1;
        #pragma unroll
        for (int j = 0; j < 8; ++j) { o0.u[j] = tile[iq + j][dc]; o1.u[j] = tile[iq + 8 + j][dc]; }
        bf16_t* dstT = xgT + ((long)seg * D_MODEL + dt * 64 + dc) * M_SUB + it * 64 + iq;
        *(bf16x8*)(dstT)     = o0.v;
        *(bf16x8*)(dstT + 8) = o1.v;
    }
}

// ---------------------------------------------------------------------------
// K2: QK GEMM. S[seg][q][k] = scale * sum_d xg[q][d]*xg[k][d], bf16 out.
// BM=64, BN=128, BK=32. grid = 16 segs * 8 mt * 4 nt = 512 blocks, 4 waves.
// Wave (wr=w>>1, wc=w&1) computes 32x64: 2x4 MFMA tiles.
// ---------------------------------------------------------------------------
__global__ __launch_bounds__(256) void qk_kernel(
    const bf16_t* __restrict__ xg, bf16_t* __restrict__ S)
{
    const int bid = blockIdx.x;
    const int seg = bid >> 5;
    const int mt  = (bid >> 2) & 7;
    const int nt  = bid & 3;

    const int tid  = threadIdx.x;
    const int w    = tid >> 6;
    const int lane = tid & 63;
    const int l16  = lane & 15;
    const int quad = lane >> 4;
    const int wr   = w >> 1, wc = w & 1;

    __shared__ alignas(16) bf16_t As[64 * 32];
    __shared__ alignas(16) bf16_t Bs[128 * 32];

    const bf16_t* xseg = xg + (long)seg * M_SUB * D_MODEL;
    // per-lane global staging bases (advance by 32 per K-step)
    const bf16_t* ga  = xseg + (long)(mt * 64 + w * 16 + (lane >> 2)) * D_MODEL + (lane & 3) * 8;
    const bf16_t* gb0 = xseg + (long)(nt * 128 + (w * 2 + 0) * 16 + (lane >> 2)) * D_MODEL + (lane & 3) * 8;
    const bf16_t* gb1 = xseg + (long)(nt * 128 + (w * 2 + 1) * 16 + (lane >> 2)) * D_MODEL + (lane & 3) * 8;
    bf16_t* la  = &As[w * 512];
    bf16_t* lb0 = &Bs[(w * 2 + 0) * 512];
    bf16_t* lb1 = &Bs[(w * 2 + 1) * 512];

    floatx4 acc[2][4];
    #pragma unroll
    for (int i = 0; i < 2; ++i)
        #pragma unroll
        for (int j = 0; j < 4; ++j) acc[i][j] = (floatx4){0.f, 0.f, 0.f, 0.f};

    for (int kk = 0; kk < D_MODEL; kk += 32) {
        __syncthreads();
        gload16(ga  + kk, la);
        gload16(gb0 + kk, lb0);
        gload16(gb1 + kk, lb1);
        __syncthreads();

        bf16x8 Af[2], Bf[4];
        #pragma unroll
        for (int m2 = 0; m2 < 2; ++m2)
            Af[m2] = *(const bf16x8*)&As[(wr * 32 + m2 * 16 + l16) * 32 + quad * 8];
        #pragma unroll
        for (int n2 = 0; n2 < 4; ++n2)
            Bf[n2] = *(const bf16x8*)&Bs[(wc * 64 + n2 * 16 + l16) * 32 + quad * 8];
        #pragma unroll
        for (int m2 = 0; m2 < 2; ++m2)
            #pragma unroll
            for (int n2 = 0; n2 < 4; ++n2)
                acc[m2][n2] = __builtin_amdgcn_mfma_f32_16x16x32_bf16(Af[m2], Bf[n2], acc[m2][n2], 0, 0, 0);
    }

    const float scale = 0.03125f;   // 1/sqrt(1024)
    bf16_t* Sseg = S + (long)seg * M_SUB * M_SUB;
    #pragma unroll
    for (int m2 = 0; m2 < 2; ++m2) {
        const int qrow = mt * 64 + wr * 32 + m2 * 16 + quad * 4;
        #pragma unroll
        for (int n2 = 0; n2 < 4; ++n2) {
            const int col = nt * 128 + wc * 64 + n2 * 16 + l16;
            #pragma unroll
            for (int rg = 0; rg < 4; ++rg)
                Sseg[(long)(qrow + rg) * M_SUB + col] = (bf16_t)(acc[m2][n2][rg] * scale);
        }
    }
}

// ---------------------------------------------------------------------------
// K3: row-wise softmax in-place on S (bf16). 1 wave per 512-row.
// ---------------------------------------------------------------------------
__global__ __launch_bounds__(256) void softmax_kernel(bf16_t* __restrict__ S)
{
    const int row  = blockIdx.x * 4 + (threadIdx.x >> 6);
    const int lane = threadIdx.x & 63;
    bf16_t* p = S + (long)row * M_SUB + lane * 8;
    bf16x8 v = *(const bf16x8*)p;
    float f[8];
    #pragma unroll
    for (int j = 0; j < 8; ++j) f[j] = (float)v[j];
    float m = f[0];
    #pragma unroll
    for (int j = 1; j < 8; ++j) m = fmaxf(m, f[j]);
    #pragma unroll
    for (int d = 1; d < 64; d <<= 1) m = fmaxf(m, __shfl_xor(m, d, 64));
    float sum = 0.f;
    #pragma unroll
    for (int j = 0; j < 8; ++j) { f[j] = __expf(f[j] - m); sum += f[j]; }
    #pragma unroll
    for (int d = 1; d < 64; d <<= 1) sum += __shfl_xor(sum, d, 64);
    const float inv = 1.0f / sum;
    #pragma unroll
    for (int j = 0; j < 8; ++j) v[j] = (bf16_t)(f[j] * inv);
    *(bf16x8*)p = v;
}

// ---------------------------------------------------------------------------
// K4: PV GEMM. out[tok][d] = sum_k P[q][k] * V[k][d],  V^T = xgT.
// BM=BN=128, BK=32. grid = 16 segs * 4 mt * 8 nt = 512 blocks, 4 waves.
// Wave computes 64x64: 4x4 MFMA tiles. Direct fp32 scatter store.
// ---------------------------------------------------------------------------
__global__ __launch_bounds__(256) void pv_kernel(
    const bf16_t* __restrict__ S, const bf16_t* __restrict__ xgT,
    const int* __restrict__ hidp, float* __restrict__ out)
{
    const int off = ((hidp[0] % RATE) + RATE) % RATE;
    const int bid = blockIdx.x;
    const int seg = bid >> 5;
    const int mt  = (bid >> 3) & 3;
    const int nt  = bid & 7;
    const int b   = seg >> 2, s = seg & 3;

    const int tid  = threadIdx.x;
    const int w    = tid >> 6;
    const int lane = tid & 63;
    const int l16  = lane & 15;
    const int quad = lane >> 4;
    const int wr   = w >> 1, wc = w & 1;

    __shared__ alignas(16) bf16_t As[128 * 32];
    __shared__ alignas(16) bf16_t Bs[128 * 32];

    const bf16_t* Aseg = S   + (long)seg * M_SUB * M_SUB + (long)mt * 128 * M_SUB;
    const bf16_t* Bseg = xgT + (long)seg * D_MODEL * M_SUB + (long)nt * 128 * M_SUB;

    const bf16_t* ga0 = Aseg + (long)((w * 2 + 0) * 16 + (lane >> 2)) * M_SUB + (lane & 3) * 8;
    const bf16_t* ga1 = Aseg + (long)((w * 2 + 1) * 16 + (lane >> 2)) * M_SUB + (lane & 3) * 8;
    const bf16_t* gb0 = Bseg + (long)((w * 2 + 0) * 16 + (lane >> 2)) * M_SUB + (lane & 3) * 8;
    const bf16_t* gb1 = Bseg + (long)((w * 2 + 1) * 16 + (lane >> 2)) * M_SUB + (lane & 3) * 8;
    bf16_t* la0 = &As[(w * 2 + 0) * 512];
    bf16_t* la1 = &As[(w * 2 + 1) * 512];
    bf16_t* lb0 = &Bs[(w * 2 + 0) * 512];
    bf16_t* lb1 = &Bs[(w * 2 + 1) * 512];

    floatx4 acc[4][4];
    #pragma unroll
    for (int i = 0; i < 4; ++i)
        #pragma unroll
        for (int j = 0; j < 4; ++j) acc[i][j] = (floatx4){0.f, 0.f, 0.f, 0.f};

    for (int kk = 0; kk < M_SUB; kk += 32) {
        __syncthreads();
        gload16(ga0 + kk, la0);
        gload16(ga1 + kk, la1);
        gload16(gb0 + kk, lb0);
        gload16(gb1 + kk, lb1);
        __syncthreads();

        bf16x8 Af[4], Bf[4];
        #pragma unroll
        for (int m2 = 0; m2 < 4; ++m2)
            Af[m2] = *(const bf16x8*)&As[(wr * 64 + m2 * 16 + l16) * 32 + quad * 8];
        #pragma unroll
        for (int n2 = 0; n2 < 4; ++n2)
            Bf[n2] = *(const bf16x8*)&Bs[(wc * 64 + n2 * 16 + l16) * 32 + quad * 8];
        #pragma unroll
        for (int m2 = 0; m2 < 4; ++m2)
            #pragma unroll
            for (int n2 = 0; n2 < 4; ++n2)
                acc[m2][n2] = __builtin_amdgcn_mfma_f32_16x16x32_bf16(Af[m2], Bf[n2], acc[m2][n2], 0, 0, 0);
    }

    float* obase = out + (long)b * NTOK * D_MODEL;
    #pragma unroll
    for (int m2 = 0; m2 < 4; ++m2) {
        const int qrow0 = mt * 128 + wr * 64 + m2 * 16 + quad * 4;
        #pragma unroll
        for (int rg = 0; rg < 4; ++rg) {
            const long tok = (long)s * SEG_W + off + 4L * (qrow0 + rg);
            float* orow = obase + tok * D_MODEL;
            #pragma unroll
            for (int n2 = 0; n2 < 4; ++n2) {
                const int d = nt * 128 + wc * 64 + n2 * 16 + l16;
                orow[d] = acc[m2][n2][rg];
            }
        }
    }
}

extern "C" void kernel_launch(void* const* d_in, const int* in_sizes, int n_in,
                              void* d_out, int out_size, void* d_ws, size_t ws_size,
                              hipStream_t stream) {
    const float* x   = (const float*)d_in[0];
    const int*   hid = (const int*)d_in[1];
    float*       out = (float*)d_out;
    bf16_t* xg  = (bf16_t*)d_ws;
    bf16_t* xgT = xg + XG_ELEMS;
    bf16_t* S   = xgT + XG_ELEMS;     // total ws: 2*16.78 + 8.39 = 41.9 MB

    zero_kernel<<<dim3(24576), dim3(256), 0, stream>>>(hid, out);
    gather_kernel<<<dim3(2048), dim3(256), 0, stream>>>(x, hid, xg, xgT);
    qk_kernel<<<dim3(512), dim3(256), 0, stream>>>(xg, S);
    softmax_kernel<<<dim3(2048), dim3(256), 0, stream>>>(S);
    pv_kernel<<<dim3(512), dim3(256), 0, stream>>>(S, xgT, hid, out);
}

// Round 4
// 248.484 us; speedup vs baseline: 1.3813x; 1.0242x over previous
//
#include <hip/hip_runtime.h>
#include <hip/hip_bf16.h>

// DilatedAttention (b=4, n=8192, d=1024, w=2048, r=4):
// 16 independent 512x512 self-attentions at d=1024 over gathered tokens
// off + 4*j per segment. alphas==1 (idx unique), so output = scatter(att).
//
// Pipeline: gather(x->xg,xgT bf16) ; QK GEMM (BK=64, xor-swizzled LDS) -> S ;
// rowwise softmax in-place ; PV GEMM -> nontemporal scatter store + fused
// zero-fill of non-idx rows in the epilogue.

typedef __bf16 bf16_t;
typedef __bf16 bf16x8 __attribute__((ext_vector_type(8)));
typedef float floatx4 __attribute__((ext_vector_type(4)));

#define D_MODEL 1024
#define SEG_W   2048
#define RATE    4
#define M_SUB   512          // tokens per segment after dilation (w/r)
#define NTOK    8192
#define NSEGT   16           // batch(4) * segments(4)
#define XG_ELEMS ((long)NSEGT * M_SUB * D_MODEL)

__device__ __forceinline__ void gload16(const bf16_t* g, bf16_t* l) {
    __builtin_amdgcn_global_load_lds(
        (const __attribute__((address_space(1))) void*)g,
        (__attribute__((address_space(3))) void*)l, 16, 0, 0);
}

// ---------------------------------------------------------------------------
// K1: gather x[b, s*2048 + off + 4i, :] -> xg bf16 [seg][i][d]
//                                       -> xgT bf16 [seg][d][i]
// ---------------------------------------------------------------------------
__global__ __launch_bounds__(256) void gather_kernel(
    const float* __restrict__ x, const int* __restrict__ hidp,
    bf16_t* __restrict__ xg, bf16_t* __restrict__ xgT)
{
    const int off = ((hidp[0] % RATE) + RATE) % RATE;
    const int bid = blockIdx.x;
    const int seg = bid >> 7;          // 0..15
    const int rem = bid & 127;
    const int it  = rem >> 4;          // i-tile 0..7
    const int dt  = rem & 15;          // d-tile 0..15
    const int b   = seg >> 2, s = seg & 3;

    __shared__ ushort tile[64][65];

    const int t  = threadIdx.x;
    const int r  = t >> 2;             // 0..63
    const int cq = (t & 3) << 4;       // 0,16,32,48

    union U8 { bf16x8 v; ushort u[8]; };

    {
        const int  i   = it * 64 + r;
        const long tok = (long)s * SEG_W + off + 4L * i;
        const float* src = x + ((long)b * NTOK + tok) * D_MODEL + dt * 64 + cq;
        float4 f0 = ((const float4*)src)[0];
        float4 f1 = ((const float4*)src)[1];
        float4 f2 = ((const float4*)src)[2];
        float4 f3 = ((const float4*)src)[3];
        U8 lo, hi;
        lo.v[0]=(bf16_t)f0.x; lo.v[1]=(bf16_t)f0.y; lo.v[2]=(bf16_t)f0.z; lo.v[3]=(bf16_t)f0.w;
        lo.v[4]=(bf16_t)f1.x; lo.v[5]=(bf16_t)f1.y; lo.v[6]=(bf16_t)f1.z; lo.v[7]=(bf16_t)f1.w;
        hi.v[0]=(bf16_t)f2.x; hi.v[1]=(bf16_t)f2.y; hi.v[2]=(bf16_t)f2.z; hi.v[3]=(bf16_t)f2.w;
        hi.v[4]=(bf16_t)f3.x; hi.v[5]=(bf16_t)f3.y; hi.v[6]=(bf16_t)f3.z; hi.v[7]=(bf16_t)f3.w;
        bf16_t* dstg = xg + ((long)seg * M_SUB + i) * D_MODEL + dt * 64 + cq;
        *(bf16x8*)(dstg)     = lo.v;
        *(bf16x8*)(dstg + 8) = hi.v;
        #pragma unroll
        for (int j = 0; j < 8; ++j) { tile[r][cq + j] = lo.u[j]; tile[r][cq + 8 + j] = hi.u[j]; }
    }
    __syncthreads();
    {
        const int dc = r;
        const int iq = cq;
        U8 o0, o1;
        #pragma unroll
        for (int j = 0; j < 8; ++j) { o0.u[j] = tile[iq + j][dc]; o1.u[j] = tile[iq + 8 + j][dc]; }
        bf16_t* dstT = xgT + ((long)seg * D_MODEL + dt * 64 + dc) * M_SUB + it * 64 + iq;
        *(bf16x8*)(dstT)     = o0.v;
        *(bf16x8*)(dstT + 8) = o1.v;
    }
}

// ---------------------------------------------------------------------------
// K2: QK GEMM. S[seg][q][k] = scale * sum_d xg[q][d]*xg[k][d], bf16 out.
// BM=64, BN=128, BK=64. grid = 16 segs * 8 mt * 4 nt = 512 blocks, 4 waves.
// XOR chunk swizzle: global 16B-chunk c of LDS row r lives at slot c^(r&7)
// -> fragment ds_read_b128 is 2-way bank aliased (free), staging stays
// wave-uniform-base + lane*16 as global_load_lds requires.
// ---------------------------------------------------------------------------
__global__ __launch_bounds__(256) void qk_kernel(
    const bf16_t* __restrict__ xg, bf16_t* __restrict__ S)
{
    const int bid = blockIdx.x;
    const int seg = bid >> 5;
    const int mt  = (bid >> 2) & 7;
    const int nt  = bid & 3;

    const int tid  = threadIdx.x;
    const int w    = tid >> 6;
    const int lane = tid & 63;
    const int l16  = lane & 15;
    const int quad = lane >> 4;
    const int wr   = w >> 1, wc = w & 1;
    const int rowin = lane >> 3;            // 0..7 row within 8-row round
    const int cswz  = ((lane & 7) ^ rowin) * 8;  // swizzled chunk offset (elems)
    const int rsw   = l16 & 7;              // fragment-row swizzle key

    __shared__ alignas(16) bf16_t As[64 * 64];    // 8 KB
    __shared__ alignas(16) bf16_t Bs[128 * 64];   // 16 KB

    const bf16_t* xseg = xg + (long)seg * M_SUB * D_MODEL;

    const bf16_t* ga0 = xseg + (long)(mt * 64 + w * 16 + rowin) * D_MODEL + cswz;
    const bf16_t* ga1 = ga0 + 8 * D_MODEL;
    const bf16_t* gb0 = xseg + (long)(nt * 128 + w * 32 + rowin) * D_MODEL + cswz;
    const bf16_t* gb1 = gb0 +  8 * D_MODEL;
    const bf16_t* gb2 = gb0 + 16 * D_MODEL;
    const bf16_t* gb3 = gb0 + 24 * D_MODEL;
    bf16_t* la0 = &As[(w * 16 + 0) * 64];
    bf16_t* la1 = &As[(w * 16 + 8) * 64];
    bf16_t* lb0 = &Bs[(w * 32 + 0) * 64];
    bf16_t* lb1 = &Bs[(w * 32 + 8) * 64];
    bf16_t* lb2 = &Bs[(w * 32 + 16) * 64];
    bf16_t* lb3 = &Bs[(w * 32 + 24) * 64];

    floatx4 acc[2][4];
    #pragma unroll
    for (int i = 0; i < 2; ++i)
        #pragma unroll
        for (int j = 0; j < 4; ++j) acc[i][j] = (floatx4){0.f, 0.f, 0.f, 0.f};

    for (int kk = 0; kk < D_MODEL; kk += 64) {
        __syncthreads();
        gload16(ga0 + kk, la0); gload16(ga1 + kk, la1);
        gload16(gb0 + kk, lb0); gload16(gb1 + kk, lb1);
        gload16(gb2 + kk, lb2); gload16(gb3 + kk, lb3);
        __syncthreads();

        #pragma unroll
        for (int ks = 0; ks < 2; ++ks) {
            bf16x8 Af[2], Bf[4];
            #pragma unroll
            for (int m2 = 0; m2 < 2; ++m2) {
                const int row = wr * 32 + m2 * 16 + l16;
                Af[m2] = *(const bf16x8*)&As[row * 64 + (((ks * 4 + quad) ^ rsw) * 8)];
            }
            #pragma unroll
            for (int n2 = 0; n2 < 4; ++n2) {
                const int row = wc * 64 + n2 * 16 + l16;
                Bf[n2] = *(const bf16x8*)&Bs[row * 64 + (((ks * 4 + quad) ^ rsw) * 8)];
            }
            #pragma unroll
            for (int m2 = 0; m2 < 2; ++m2)
                #pragma unroll
                for (int n2 = 0; n2 < 4; ++n2)
                    acc[m2][n2] = __builtin_amdgcn_mfma_f32_16x16x32_bf16(Af[m2], Bf[n2], acc[m2][n2], 0, 0, 0);
        }
    }

    const float scale = 0.03125f;   // 1/sqrt(1024)
    bf16_t* Sseg = S + (long)seg * M_SUB * M_SUB;
    #pragma unroll
    for (int m2 = 0; m2 < 2; ++m2) {
        const int qrow = mt * 64 + wr * 32 + m2 * 16 + quad * 4;
        #pragma unroll
        for (int n2 = 0; n2 < 4; ++n2) {
            const int col = nt * 128 + wc * 64 + n2 * 16 + l16;
            #pragma unroll
            for (int rg = 0; rg < 4; ++rg)
                Sseg[(long)(qrow + rg) * M_SUB + col] = (bf16_t)(acc[m2][n2][rg] * scale);
        }
    }
}

// ---------------------------------------------------------------------------
// K3: row-wise softmax in-place on S (bf16). 1 wave per 512-row.
// ---------------------------------------------------------------------------
__global__ __launch_bounds__(256) void softmax_kernel(bf16_t* __restrict__ S)
{
    const int row  = blockIdx.x * 4 + (threadIdx.x >> 6);
    const int lane = threadIdx.x & 63;
    bf16_t* p = S + (long)row * M_SUB + lane * 8;
    bf16x8 v = *(const bf16x8*)p;
    float f[8];
    #pragma unroll
    for (int j = 0; j < 8; ++j) f[j] = (float)v[j];
    float m = f[0];
    #pragma unroll
    for (int j = 1; j < 8; ++j) m = fmaxf(m, f[j]);
    #pragma unroll
    for (int d = 1; d < 64; d <<= 1) m = fmaxf(m, __shfl_xor(m, d, 64));
    float sum = 0.f;
    #pragma unroll
    for (int j = 0; j < 8; ++j) { f[j] = __expf(f[j] - m); sum += f[j]; }
    #pragma unroll
    for (int d = 1; d < 64; d <<= 1) sum += __shfl_xor(sum, d, 64);
    const float inv = 1.0f / sum;
    #pragma unroll
    for (int j = 0; j < 8; ++j) v[j] = (bf16_t)(f[j] * inv);
    *(bf16x8*)p = v;
}

// ---------------------------------------------------------------------------
// K4: PV GEMM + fused zero-fill. out[tok][d] = sum_k P[q][k]*V[k][d], V^T=xgT.
// BM=BN=128, BK=64. grid = 16 segs * 4 mt * 8 nt = 512 blocks, 4 waves.
// Epilogue: nontemporal result scatter + nontemporal zero of the 3*128
// non-idx token rows in this block's (token-span, column) range.
// ---------------------------------------------------------------------------
__global__ __launch_bounds__(256) void pv_kernel(
    const bf16_t* __restrict__ S, const bf16_t* __restrict__ xgT,
    const int* __restrict__ hidp, float* __restrict__ out)
{
    const int off = ((hidp[0] % RATE) + RATE) % RATE;
    const int bid = blockIdx.x;
    const int seg = bid >> 5;
    const int mt  = (bid >> 3) & 3;
    const int nt  = bid & 7;
    const int b   = seg >> 2, s = seg & 3;

    const int tid  = threadIdx.x;
    const int w    = tid >> 6;
    const int lane = tid & 63;
    const int l16  = lane & 15;
    const int quad = lane >> 4;
    const int wr   = w >> 1, wc = w & 1;
    const int rowin = lane >> 3;
    const int cswz  = ((lane & 7) ^ rowin) * 8;
    const int rsw   = l16 & 7;

    __shared__ alignas(16) bf16_t As[128 * 64];   // 16 KB
    __shared__ alignas(16) bf16_t Bs[128 * 64];   // 16 KB

    const bf16_t* Aseg = S   + (long)seg * M_SUB * M_SUB  + (long)mt * 128 * M_SUB;
    const bf16_t* Bseg = xgT + (long)seg * D_MODEL * M_SUB + (long)nt * 128 * M_SUB;

    const bf16_t* ga0 = Aseg + (long)(w * 32 + rowin) * M_SUB + cswz;
    const bf16_t* ga1 = ga0 +  8 * M_SUB;
    const bf16_t* ga2 = ga0 + 16 * M_SUB;
    const bf16_t* ga3 = ga0 + 24 * M_SUB;
    const bf16_t* gb0 = Bseg + (long)(w * 32 + rowin) * M_SUB + cswz;
    const bf16_t* gb1 = gb0 +  8 * M_SUB;
    const bf16_t* gb2 = gb0 + 16 * M_SUB;
    const bf16_t* gb3 = gb0 + 24 * M_SUB;
    bf16_t* la0 = &As[(w * 32 + 0) * 64];
    bf16_t* la1 = &As[(w * 32 + 8) * 64];
    bf16_t* la2 = &As[(w * 32 + 16) * 64];
    bf16_t* la3 = &As[(w * 32 + 24) * 64];
    bf16_t* lb0 = &Bs[(w * 32 + 0) * 64];
    bf16_t* lb1 = &Bs[(w * 32 + 8) * 64];
    bf16_t* lb2 = &Bs[(w * 32 + 16) * 64];
    bf16_t* lb3 = &Bs[(w * 32 + 24) * 64];

    floatx4 acc[4][4];
    #pragma unroll
    for (int i = 0; i < 4; ++i)
        #pragma unroll
        for (int j = 0; j < 4; ++j) acc[i][j] = (floatx4){0.f, 0.f, 0.f, 0.f};

    for (int kk = 0; kk < M_SUB; kk += 64) {
        __syncthreads();
        gload16(ga0 + kk, la0); gload16(ga1 + kk, la1);
        gload16(ga2 + kk, la2); gload16(ga3 + kk, la3);
        gload16(gb0 + kk, lb0); gload16(gb1 + kk, lb1);
        gload16(gb2 + kk, lb2); gload16(gb3 + kk, lb3);
        __syncthreads();

        #pragma unroll
        for (int ks = 0; ks < 2; ++ks) {
            bf16x8 Af[4], Bf[4];
            #pragma unroll
            for (int m2 = 0; m2 < 4; ++m2) {
                const int row = wr * 64 + m2 * 16 + l16;
                Af[m2] = *(const bf16x8*)&As[row * 64 + (((ks * 4 + quad) ^ rsw) * 8)];
            }
            #pragma unroll
            for (int n2 = 0; n2 < 4; ++n2) {
                const int row = wc * 64 + n2 * 16 + l16;
                Bf[n2] = *(const bf16x8*)&Bs[row * 64 + (((ks * 4 + quad) ^ rsw) * 8)];
            }
            #pragma unroll
            for (int m2 = 0; m2 < 4; ++m2)
                #pragma unroll
                for (int n2 = 0; n2 < 4; ++n2)
                    acc[m2][n2] = __builtin_amdgcn_mfma_f32_16x16x32_bf16(Af[m2], Bf[n2], acc[m2][n2], 0, 0, 0);
        }
    }

    // ---- result scatter (nontemporal: not re-read)
    float* obase = out + (long)b * NTOK * D_MODEL;
    #pragma unroll
    for (int m2 = 0; m2 < 4; ++m2) {
        const int qrow0 = mt * 128 + wr * 64 + m2 * 16 + quad * 4;
        #pragma unroll
        for (int rg = 0; rg < 4; ++rg) {
            const long tok = (long)s * SEG_W + off + 4L * (qrow0 + rg);
            float* orow = obase + tok * D_MODEL;
            #pragma unroll
            for (int n2 = 0; n2 < 4; ++n2) {
                const int d = nt * 128 + wc * 64 + n2 * 16 + l16;
                __builtin_nontemporal_store(acc[m2][n2][rg], &orow[d]);
            }
        }
    }

    // ---- fused zero-fill: 3*128 non-idx rows in this block's span/columns
    {
        const floatx4 z = {0.f, 0.f, 0.f, 0.f};
        const int zr = tid >> 5;        // 0..7
        const int zc = tid & 31;        // float4 chunk within 128 cols
        #pragma unroll 4
        for (int p = 0; p < 48; ++p) {
            const int j = p * 8 + zr;   // 0..383
            const int q = j / 3, e = j % 3;
            const int delta = e + (e >= off ? 1 : 0);
            const long tok = (long)s * SEG_W + 4L * (mt * 128 + q) + delta;
            float* dst = obase + tok * D_MODEL + nt * 128 + zc * 4;
            __builtin_nontemporal_store(z, (floatx4*)dst);
        }
    }
}

extern "C" void kernel_launch(void* const* d_in, const int* in_sizes, int n_in,
                              void* d_out, int out_size, void* d_ws, size_t ws_size,
                              hipStream_t stream) {
    const float* x   = (const float*)d_in[0];
    const int*   hid = (const int*)d_in[1];
    float*       out = (float*)d_out;
    bf16_t* xg  = (bf16_t*)d_ws;
    bf16_t* xgT = xg + XG_ELEMS;
    bf16_t* S   = xgT + XG_ELEMS;     // total ws: 2*16.78 + 8.39 = 41.9 MB

    gather_kernel<<<dim3(2048), dim3(256), 0, stream>>>(x, hid, xg, xgT);
    qk_kernel<<<dim3(512), dim3(256), 0, stream>>>(xg, S);
    softmax_kernel<<<dim3(2048), dim3(256), 0, stream>>>(S);
    pv_kernel<<<dim3(512), dim3(256), 0, stream>>>(S, xgT, hid, out);
}